// Round 12
// baseline (85.066 us; speedup 1.0000x reference)
//
#include <hip/hip_runtime.h>

typedef short  bf16x8   __attribute__((ext_vector_type(8)));
typedef float  f32x16   __attribute__((ext_vector_type(16)));

#define JS      13           // j-splits (grid.y)
#define STREAMS (JS * 4)     // 52 wave-streams per i-tile (stride in j-tiles)
#define TI      128          // i-points per block (4 MFMA groups per A-load)
#define DEPTH   2            // prefetch depth (buffers X/Y)

__device__ __forceinline__ unsigned short f2bf(float x) {
    unsigned u = __builtin_bit_cast(unsigned, x);
    u += 0x7FFF + ((u >> 16) & 1);          // RNE
    return (unsigned short)(u >> 16);
}
__device__ __forceinline__ float bf2f(unsigned short h) {
    unsigned u = ((unsigned)h) << 16;
    return __builtin_bit_cast(float, u);
}

// ---- pack padding points into MFMA-A planes + zero the output ----
// Row j (K=16 bf16): k0-2 qh | k3-5 ql | k6-8 qh | k9-11 ql | k12-13 negc h/l |
// k14-15 = 1.0,1.0 (pair B's -ha hi/lo threshold fold).
// plane0 = k0-7 (lanes 0-31), plane1 = k8-15 (lanes 32-63).
__global__ __launch_bounds__(256) void dens_pack_kernel(
    const float* __restrict__ pad, uint4* __restrict__ ws,
    int* __restrict__ out, int M, int mtot, int N)
{
    const int j = blockIdx.x * 256 + threadIdx.x;
    if (j < N) out[j] = 0;                      // fold output zeroing here
    if (j >= mtot) return;

    float qx = 0.f, qy = 0.f, qz = 0.f;
    float negc = -1.0e6f;                       // padded rows: s<0 -> sign -1 cancels baseline
    if (j < M) {
        qx = pad[3 * j]; qy = pad[3 * j + 1]; qz = pad[3 * j + 2];
        negc = 0.125f - 0.5f * (qx * qx + qy * qy + qz * qz);   // (r^2 - |q|^2)/2
    }
    const unsigned short xh = f2bf(qx), yh = f2bf(qy), zh = f2bf(qz);
    const unsigned short xl = f2bf(qx - bf2f(xh));
    const unsigned short yl = f2bf(qy - bf2f(yh));
    const unsigned short zl = f2bf(qz - bf2f(zh));
    const unsigned short ch = f2bf(negc);
    const unsigned short cl = f2bf(negc - bf2f(ch));

    uint4 p0, p1;
    p0.x = (unsigned)xh | ((unsigned)yh << 16);   // k0,k1
    p0.y = (unsigned)zh | ((unsigned)xl << 16);   // k2,k3
    p0.z = (unsigned)yl | ((unsigned)zl << 16);   // k4,k5
    p0.w = (unsigned)xh | ((unsigned)yh << 16);   // k6,k7
    p1.x = (unsigned)zh | ((unsigned)xl << 16);   // k8,k9
    p1.y = (unsigned)yl | ((unsigned)zl << 16);   // k10,k11
    p1.z = (unsigned)ch | ((unsigned)cl << 16);   // k12,k13
    p1.w = 0x3F803F80u;                           // k14,k15 = 1.0,1.0
    ws[j]        = p0;                            // plane0
    ws[mtot + j] = p1;                            // plane1
}

// B-frag with threshold folded into k14/k15: s = p.q + negc - ha, within <=> s>=0.
__device__ __forceinline__ void make_bfrag(const float* __restrict__ pc,
                                           int i, int N, int half, bf16x8& B)
{
    float px = 0.f, py = 0.f, pz = 0.f;
    float ha = 3.0e38f;                          // i-pad: s ~ -3e38 < 0 always
    if (i < N) {
        px = pc[3 * i]; py = pc[3 * i + 1]; pz = pc[3 * i + 2];
        ha = 0.5f * (px * px + py * py + pz * pz);   // |p|^2/2, fp32
    }
    const float nha = -ha;
    const unsigned short nhh = f2bf(nha);
    const unsigned short nhl = f2bf(nha - bf2f(nhh));   // 2-term split, err ~1e-5
    const short xh = (short)f2bf(px), yh = (short)f2bf(py), zh = (short)f2bf(pz);
    const short xl = (short)f2bf(px - bf2f((unsigned short)xh));
    const short yl = (short)f2bf(py - bf2f((unsigned short)yh));
    const short zl = (short)f2bf(pz - bf2f((unsigned short)zh));
    const short ONE = (short)0x3F80;
    const bf16x8 Blo = {xh, yh, zh, xh, yh, zh, xl, yl};                    // k0-7
    const bf16x8 Bhi = {zl, xl, yl, zl, ONE, ONE, (short)nhh, (short)nhl};  // k8-15
    B = half ? Bhi : Blo;
}

// ---- sign word: 4 f32 D values -> 1 word of 4 bytes {0x01 miss | 0x00} ----
// Same proven perm-gather as R9 (byte3 = sign|exp[7:1]); then >>7 & 0x01010101
// moves each byte's sign bit to bit0 (cross-byte bleed masked off).
__device__ __forceinline__ unsigned sgnw(float f0, float f1, float f2, float f3) {
    const unsigned u0 = __builtin_bit_cast(unsigned, f0);
    const unsigned u1 = __builtin_bit_cast(unsigned, f1);
    const unsigned u2 = __builtin_bit_cast(unsigned, f2);
    const unsigned u3 = __builtin_bit_cast(unsigned, f3);
    const unsigned lo = __builtin_amdgcn_perm(u0, u1, 0x0C0C0703u);  // {u1.b3,u0.b3,0,0}
    const unsigned hi = __builtin_amdgcn_perm(u2, u3, 0x07030C0Cu);  // {0,0,u3.b3,u2.b3}
    return ((lo | hi) >> 7) & 0x01010101u;
}

// bytewise-accumulator epilogue: acc bytes <= 64; sum the 4 bytes exactly.
__device__ __forceinline__ int bytesum(unsigned a) {
    const unsigned s = (a & 0x00FF00FFu) + ((a >> 8) & 0x00FF00FFu);
    return (int)((s & 0xFFFFu) + (s >> 16));
}

// grid (157 x 13), 256 thr. 128-wide i-tile; 52 wave-streams stride j-tiles.
// R9 structure, SINGLE CHANGE: i8-MFMA reduction -> per-lane VALU byte-count.
// bf16 D-layout: each lane's 16 f32 = 16 j-rows of ONE column i (=lane&31),
// so the reduction is lane-local. Per visit the MFMA pipe demand halves
// (256 -> 128 cyc/SIMD; corrected constant: 32x32 MFMA = ~32 cyc/SIMD) and
// the serial i8 acc-chain disappears; VALU rises 132 -> ~180 cyc (byte adds:
// each byte counts <=2/visit x16 visits = 32 <= 255, no overflow).
// 16 visits, 8 iterations of 2 visits; DEPTH=2 marching buffers X/Y.
__global__ __launch_bounds__(256, 4) void dens_mfma_kernel(
    const float* __restrict__ pc,     // [N,3] pointcloud
    const char*  __restrict__ wsA,    // packed A planes ((visits+DEPTH)*STREAMS tiles)
    int* __restrict__ out,            // [N] counts (pre-zeroed)
    int N, int iters, int p1off, int visits)
{
    const int lane = threadIdx.x & 63;
    const int w    = threadIdx.x >> 6;   // wave 0..3
    const int n    = lane & 31;          // output col within 32-tile = i
    const int half = lane >> 5;          // k-chunk 0/1

    const int ibase = blockIdx.x * TI;
    bf16x8 B0, B1, B2, B3;
    make_bfrag(pc, ibase + n,      N, half, B0);
    make_bfrag(pc, ibase + 32 + n, N, half, B1);
    make_bfrag(pc, ibase + 64 + n, N, half, B2);
    make_bfrag(pc, ibase + 96 + n, N, half, B3);

    const int stream = blockIdx.y * 4 + w;          // 0..51
    // marching A-plane pointer; tile stride 0x6800 B = 1664 uint4
    const uint4* __restrict__ ap = (const uint4*)
        (wsA + (half ? p1off : 0) + n * 16 + (size_t)stream * 512);
    const int T4 = 0x6800 / 16;

    const f32x16 z = {0.f};         // zero C operand, held in regs

    // bytewise miss accumulators: one A/B pair per group (named, no arrays)
    unsigned a0A = 0, a0B = 0, a1A = 0, a1B = 0;
    unsigned a2A = 0, a2B = 0, a3A = 0, a3B = 0;

    uint4 X = ap[0];
    uint4 Y = ap[T4];
    int nextoff = 2 * T4;

#define GROUPV(AV, BV, AA, AB) { \
        f32x16 d = __builtin_amdgcn_mfma_f32_32x32x16_bf16(AV, BV, z, 0, 0, 0); \
        AA += sgnw(d[0], d[1], d[2],  d[3])  + sgnw(d[4],  d[5],  d[6],  d[7]); \
        AB += sgnw(d[8], d[9], d[10], d[11]) + sgnw(d[12], d[13], d[14], d[15]); }

    for (int t = 0; t < iters; ++t) {
        {   // visit A: consume X, refill X two tiles ahead
            const bf16x8 a = __builtin_bit_cast(bf16x8, X);
            GROUPV(a, B0, a0A, a0B)
            GROUPV(a, B1, a1A, a1B)
            GROUPV(a, B2, a2A, a2B)
            GROUPV(a, B3, a3A, a3B)
            X = ap[nextoff]; nextoff += T4;
        }
        {   // visit B: consume Y, refill Y
            const bf16x8 a = __builtin_bit_cast(bf16x8, Y);
            GROUPV(a, B0, a0A, a0B)
            GROUPV(a, B1, a1A, a1B)
            GROUPV(a, B2, a2A, a2B)
            GROUPV(a, B3, a3A, a3B)
            Y = ap[nextoff]; nextoff += T4;
        }
    }
#undef GROUPV

    // Per (lane, group): miss count for column i = 32g+n over this lane's 16
    // j-rows x visits (byte-exact). Lane n and n+32 hold disjoint row-halves
    // of the same column -> combine via shfl_xor(32). Per-wave contribution
    // for i = 32*visits - miss_total (padded j rows: s<0 -> miss, cancels).
    const int base = 32 * visits;
    int m0 = bytesum(a0A + a0B);
    int m1 = bytesum(a1A + a1B);
    int m2 = bytesum(a2A + a2B);
    int m3 = bytesum(a3A + a3B);
    m0 += __shfl_xor(m0, 32);
    m1 += __shfl_xor(m1, 32);
    m2 += __shfl_xor(m2, 32);
    m3 += __shfl_xor(m3, 32);

    __shared__ int red[4][TI];
    if (lane < 32) {
        red[w][n]      = base - m0;
        red[w][n + 32] = base - m1;
        red[w][n + 64] = base - m2;
        red[w][n + 96] = base - m3;
    }
    __syncthreads();
    if (threadIdx.x < TI) {
        const int ii = ibase + threadIdx.x;
        if (ii < N) {
            const int s = red[0][threadIdx.x] + red[1][threadIdx.x] +
                          red[2][threadIdx.x] + red[3][threadIdx.x];
            atomicAdd(&out[ii], s);
        }
    }
}

extern "C" void kernel_launch(void* const* d_in, const int* in_sizes, int n_in,
                              void* d_out, int out_size, void* d_ws, size_t ws_size,
                              hipStream_t stream) {
    const float* pc  = (const float*)d_in[0];   // [N,3] pointcloud
    const float* pad = (const float*)d_in[1];   // [M,3] pointcloud_padding
    int* out = (int*)d_out;

    const int N = in_sizes[0] / 3;              // 20000
    const int M = in_sizes[1] / 3;              // 25000
    const int jt = (M + 31) / 32;               // 782 j-tiles
    int visits = (jt + STREAMS - 1) / STREAMS;  // 16
    if (visits & 1) visits++;                   // 2-visit unrolled body
    const int jtp  = (visits + DEPTH) * STREAMS;    // 936 tiles incl. prefetch overrun
    const int mtot = jtp * 32;                  // 29952 rows (~958 KB in ws)

    dens_pack_kernel<<<(mtot + 255) / 256, 256, 0, stream>>>(
        pad, (uint4*)d_ws, out, M, mtot, N);

    dim3 grid((N + TI - 1) / TI, JS);           // 157 x 13
    dens_mfma_kernel<<<grid, 256, 0, stream>>>(
        pc, (const char*)d_ws, out, N, visits / 2, mtot * 16, visits);
}

// Round 13
// 82.940 us; speedup vs baseline: 1.0256x; 1.0256x over previous
//
#include <hip/hip_runtime.h>

typedef short  bf16x8   __attribute__((ext_vector_type(8)));
typedef int    int32x4  __attribute__((ext_vector_type(4)));
typedef int    int32x16 __attribute__((ext_vector_type(16)));
typedef float  f32x16   __attribute__((ext_vector_type(16)));

#define JS      13           // j-splits (grid.y)
#define STREAMS (JS * 4)     // 52 wave-streams per i-tile (stride in j-tiles)
#define TI      128          // i-points per block (4 MFMA groups per A-load)
#define DEPTH   2            // prefetch depth (buffers X/Y)

__device__ __forceinline__ unsigned short f2bf(float x) {
    unsigned u = __builtin_bit_cast(unsigned, x);
    u += 0x7FFF + ((u >> 16) & 1);          // RNE
    return (unsigned short)(u >> 16);
}
__device__ __forceinline__ float bf2f(unsigned short h) {
    unsigned u = ((unsigned)h) << 16;
    return __builtin_bit_cast(float, u);
}

// ---- pack padding points into MFMA-A planes + zero the output ----
// Row j (K=16 bf16): k0-2 qh | k3-5 ql | k6-8 qh | k9-11 ql | k12-13 negc h/l |
// k14-15 = 1.0,1.0 (pair B's -ha hi/lo threshold fold).
// plane0 = k0-7 (lanes 0-31), plane1 = k8-15 (lanes 32-63).
__global__ __launch_bounds__(256) void dens_pack_kernel(
    const float* __restrict__ pad, uint4* __restrict__ ws,
    int* __restrict__ out, int M, int mtot, int N)
{
    const int j = blockIdx.x * 256 + threadIdx.x;
    if (j < N) out[j] = 0;                      // fold output zeroing here
    if (j >= mtot) return;

    float qx = 0.f, qy = 0.f, qz = 0.f;
    float negc = -1.0e6f;                       // padded rows: s<0 -> sign -1 cancels baseline
    if (j < M) {
        qx = pad[3 * j]; qy = pad[3 * j + 1]; qz = pad[3 * j + 2];
        negc = 0.125f - 0.5f * (qx * qx + qy * qy + qz * qz);   // (r^2 - |q|^2)/2
    }
    const unsigned short xh = f2bf(qx), yh = f2bf(qy), zh = f2bf(qz);
    const unsigned short xl = f2bf(qx - bf2f(xh));
    const unsigned short yl = f2bf(qy - bf2f(yh));
    const unsigned short zl = f2bf(qz - bf2f(zh));
    const unsigned short ch = f2bf(negc);
    const unsigned short cl = f2bf(negc - bf2f(ch));

    uint4 p0, p1;
    p0.x = (unsigned)xh | ((unsigned)yh << 16);   // k0,k1
    p0.y = (unsigned)zh | ((unsigned)xl << 16);   // k2,k3
    p0.z = (unsigned)yl | ((unsigned)zl << 16);   // k4,k5
    p0.w = (unsigned)xh | ((unsigned)yh << 16);   // k6,k7
    p1.x = (unsigned)zh | ((unsigned)xl << 16);   // k8,k9
    p1.y = (unsigned)yl | ((unsigned)zl << 16);   // k10,k11
    p1.z = (unsigned)ch | ((unsigned)cl << 16);   // k12,k13
    p1.w = 0x3F803F80u;                           // k14,k15 = 1.0,1.0
    ws[j]        = p0;                            // plane0
    ws[mtot + j] = p1;                            // plane1
}

// B-frag with threshold folded into k14/k15: s = p.q + negc - ha, within <=> s>=0.
__device__ __forceinline__ void make_bfrag(const float* __restrict__ pc,
                                           int i, int N, int half, bf16x8& B)
{
    float px = 0.f, py = 0.f, pz = 0.f;
    float ha = 3.0e38f;                          // i-pad: s ~ -3e38 < 0 always
    if (i < N) {
        px = pc[3 * i]; py = pc[3 * i + 1]; pz = pc[3 * i + 2];
        ha = 0.5f * (px * px + py * py + pz * pz);   // |p|^2/2, fp32
    }
    const float nha = -ha;
    const unsigned short nhh = f2bf(nha);
    const unsigned short nhl = f2bf(nha - bf2f(nhh));   // 2-term split, err ~1e-5
    const short xh = (short)f2bf(px), yh = (short)f2bf(py), zh = (short)f2bf(pz);
    const short xl = (short)f2bf(px - bf2f((unsigned short)xh));
    const short yl = (short)f2bf(py - bf2f((unsigned short)yh));
    const short zl = (short)f2bf(pz - bf2f((unsigned short)zh));
    const short ONE = (short)0x3F80;
    const bf16x8 Blo = {xh, yh, zh, xh, yh, zh, xl, yl};                    // k0-7
    const bf16x8 Bhi = {zl, xl, yl, zl, ONE, ONE, (short)nhh, (short)nhl};  // k8-15
    B = half ? Bhi : Blo;
}

// ---- packed sign-byte gather: 4 f32 D values -> 1 word of 4 bytes {0x80|0} ----
// v_perm_b32: D.byte[i] = sel.byte[i] in 0-3 -> S1.byte[sel], 4-7 -> S0.byte[sel-4],
// 0x0C -> 0x00. byte3 of an f32 = sign|exp[7:1]; AND 0x80 isolates the sign.
// Byte order within the word is irrelevant (all 32 indicators are summed).
__device__ __forceinline__ unsigned pack4(float f0, float f1, float f2, float f3) {
    const unsigned u0 = __builtin_bit_cast(unsigned, f0);
    const unsigned u1 = __builtin_bit_cast(unsigned, f1);
    const unsigned u2 = __builtin_bit_cast(unsigned, f2);
    const unsigned u3 = __builtin_bit_cast(unsigned, f3);
    const unsigned lo = __builtin_amdgcn_perm(u0, u1, 0x0C0C0703u);  // {u1.b3,u0.b3,0,0}
    const unsigned hi = __builtin_amdgcn_perm(u2, u3, 0x07030C0Cu);  // {0,0,u3.b3,u2.b3}
    return (lo | hi) & 0x80808080u;
}

// ONE i8 MFMA reduces a packed D bank: A row r = lane&31 = local i; lane-halves
// supply k=0..15 / 16..31 -> all 32 j-indicators summed per i. A bytes are
// -128 (miss) / 0 (within); B mask 0x01 only in group-g's 8 cols -> four
// i-groups share one 16-reg i32 acc bank. acc = -128 * miss.
__device__ __forceinline__ int32x16 red_group(const f32x16 d, int32x4 m, int32x16 acc) {
    int32x4 P;
    P[0] = (int)pack4(d[0],  d[1],  d[2],  d[3]);
    P[1] = (int)pack4(d[4],  d[5],  d[6],  d[7]);
    P[2] = (int)pack4(d[8],  d[9],  d[10], d[11]);
    P[3] = (int)pack4(d[12], d[13], d[14], d[15]);
    return __builtin_amdgcn_mfma_i32_32x32x32_i8(P, m, acc, 0, 0, 0);
}

// grid (157 x 13), 256 thr. 128-wide i-tile; 52 wave-streams stride j-tiles.
// R9 structure, SINGLE CHANGE: SPLIT i8 ACCUMULATOR CHAIN. R9 chained all 64
// i8 MFMAs through one acc (serial RAW chain of long-latency ops). Here
// A-visits accumulate into acc, B-visits into acc2 (integer-exact merge in
// the epilogue): chain depth halves and adjacent links on each chain are
// separated by a full visit (~300+ cyc) of independent work. Same instruction
// count, same occupancy — an unconfounded test of chain-latency binding
// (R12's chain removal was confounded by +30 VALU ops and regressed).
// 16 visits, 8 iterations of 2 visits; DEPTH=2 marching buffers X/Y.
__global__ __launch_bounds__(256, 4) void dens_mfma_kernel(
    const float* __restrict__ pc,     // [N,3] pointcloud
    const char*  __restrict__ wsA,    // packed A planes ((visits+DEPTH)*STREAMS tiles)
    int* __restrict__ out,            // [N] counts (pre-zeroed)
    int N, int iters, int p1off, int visits)
{
    const int lane = threadIdx.x & 63;
    const int w    = threadIdx.x >> 6;   // wave 0..3
    const int n    = lane & 31;          // output col within 32-tile = i
    const int half = lane >> 5;          // k-chunk 0/1

    const int ibase = blockIdx.x * TI;
    bf16x8 B0, B1, B2, B3;
    make_bfrag(pc, ibase + n,      N, half, B0);
    make_bfrag(pc, ibase + 32 + n, N, half, B1);
    make_bfrag(pc, ibase + 64 + n, N, half, B2);
    make_bfrag(pc, ibase + 96 + n, N, half, B3);

    // per-group column masks for the i8 reduction B operand: lane covers
    // output col (lane&31); group g owns cols 8g..8g+7 of the shared acc.
    const int gsel = n >> 3;
    const int m0 = (gsel == 0) ? 0x01010101 : 0;
    const int m1 = (gsel == 1) ? 0x01010101 : 0;
    const int m2 = (gsel == 2) ? 0x01010101 : 0;
    const int m3 = (gsel == 3) ? 0x01010101 : 0;
    const int32x4 R0 = {m0, m0, m0, m0};
    const int32x4 R1 = {m1, m1, m1, m1};
    const int32x4 R2 = {m2, m2, m2, m2};
    const int32x4 R3 = {m3, m3, m3, m3};

    const int stream = blockIdx.y * 4 + w;          // 0..51
    // marching A-plane pointer; tile stride 0x6800 B = 1664 uint4
    const uint4* __restrict__ ap = (const uint4*)
        (wsA + (half ? p1off : 0) + n * 16 + (size_t)stream * 512);
    const int T4 = 0x6800 / 16;

    const f32x16  z    = {0.f};     // zero C operand, held in regs
    int32x16      acc  = {0};       // chain 1: A-visits
    int32x16      acc2 = {0};       // chain 2: B-visits

    uint4 X = ap[0];
    uint4 Y = ap[T4];
    int nextoff = 2 * T4;

#define GROUPV(AV, BV, RV, AC) { \
        f32x16 d = __builtin_amdgcn_mfma_f32_32x32x16_bf16(AV, BV, z, 0, 0, 0); \
        AC = red_group(d, RV, AC); }

    for (int t = 0; t < iters; ++t) {
        {   // visit A: consume X -> chain acc, refill X two tiles ahead
            const bf16x8 a = __builtin_bit_cast(bf16x8, X);
            GROUPV(a, B0, R0, acc)
            GROUPV(a, B1, R1, acc)
            GROUPV(a, B2, R2, acc)
            GROUPV(a, B3, R3, acc)
            X = ap[nextoff]; nextoff += T4;
        }
        {   // visit B: consume Y -> chain acc2, refill Y
            const bf16x8 a = __builtin_bit_cast(bf16x8, Y);
            GROUPV(a, B0, R0, acc2)
            GROUPV(a, B1, R1, acc2)
            GROUPV(a, B2, R2, acc2)
            GROUPV(a, B3, R3, acc2)
            Y = ap[nextoff]; nextoff += T4;
        }
    }
#undef GROUPV

    // acc D-layout (32x32 i32): col = lane&31 (group g = col>>3, value
    // replicated across the 8 cols of its range), row = (q&3)+8*(q>>2)+4*half
    // = local i. acc+acc2 = -128 * (#not-within) over this wave's 32*visits
    // j's -> per-i count for this wave = 32*visits + ((acc+acc2) >> 7).
    const int base = 32 * visits;
    __shared__ int red[4][TI];
    if ((lane & 7) == 0) {                       // one writer per (group,half)
        const int g   = n >> 3;
        const int hi4 = half << 2;               // +4 rows for upper lane-half
        int* rw = &red[w][32 * g];
        rw[ 0 + hi4] = base + ((acc[0]  + acc2[0])  >> 7);
        rw[ 1 + hi4] = base + ((acc[1]  + acc2[1])  >> 7);
        rw[ 2 + hi4] = base + ((acc[2]  + acc2[2])  >> 7);
        rw[ 3 + hi4] = base + ((acc[3]  + acc2[3])  >> 7);
        rw[ 8 + hi4] = base + ((acc[4]  + acc2[4])  >> 7);
        rw[ 9 + hi4] = base + ((acc[5]  + acc2[5])  >> 7);
        rw[10 + hi4] = base + ((acc[6]  + acc2[6])  >> 7);
        rw[11 + hi4] = base + ((acc[7]  + acc2[7])  >> 7);
        rw[16 + hi4] = base + ((acc[8]  + acc2[8])  >> 7);
        rw[17 + hi4] = base + ((acc[9]  + acc2[9])  >> 7);
        rw[18 + hi4] = base + ((acc[10] + acc2[10]) >> 7);
        rw[19 + hi4] = base + ((acc[11] + acc2[11]) >> 7);
        rw[24 + hi4] = base + ((acc[12] + acc2[12]) >> 7);
        rw[25 + hi4] = base + ((acc[13] + acc2[13]) >> 7);
        rw[26 + hi4] = base + ((acc[14] + acc2[14]) >> 7);
        rw[27 + hi4] = base + ((acc[15] + acc2[15]) >> 7);
    }
    __syncthreads();
    if (threadIdx.x < TI) {
        const int ii = ibase + threadIdx.x;
        if (ii < N) {
            const int s = red[0][threadIdx.x] + red[1][threadIdx.x] +
                          red[2][threadIdx.x] + red[3][threadIdx.x];
            atomicAdd(&out[ii], s);
        }
    }
}

extern "C" void kernel_launch(void* const* d_in, const int* in_sizes, int n_in,
                              void* d_out, int out_size, void* d_ws, size_t ws_size,
                              hipStream_t stream) {
    const float* pc  = (const float*)d_in[0];   // [N,3] pointcloud
    const float* pad = (const float*)d_in[1];   // [M,3] pointcloud_padding
    int* out = (int*)d_out;

    const int N = in_sizes[0] / 3;              // 20000
    const int M = in_sizes[1] / 3;              // 25000
    const int jt = (M + 31) / 32;               // 782 j-tiles
    int visits = (jt + STREAMS - 1) / STREAMS;  // 16
    if (visits & 1) visits++;                   // 2-visit unrolled body
    const int jtp  = (visits + DEPTH) * STREAMS;    // 936 tiles incl. prefetch overrun
    const int mtot = jtp * 32;                  // 29952 rows (~958 KB in ws)

    dens_pack_kernel<<<(mtot + 255) / 256, 256, 0, stream>>>(
        pad, (uint4*)d_ws, out, M, mtot, N);

    dim3 grid((N + TI - 1) / TI, JS);           // 157 x 13
    dens_mfma_kernel<<<grid, 256, 0, stream>>>(
        pc, (const char*)d_ws, out, N, visits / 2, mtot * 16, visits);
}

// Round 14
// 82.672 us; speedup vs baseline: 1.0290x; 1.0032x over previous
//
#include <hip/hip_runtime.h>

typedef short  bf16x8   __attribute__((ext_vector_type(8)));
typedef int    int32x4  __attribute__((ext_vector_type(4)));
typedef int    int32x16 __attribute__((ext_vector_type(16)));
typedef float  f32x16   __attribute__((ext_vector_type(16)));

#define JS      13           // j-splits (grid.y)
#define STREAMS (JS * 4)     // 52 wave-streams per i-tile (stride in j-tiles)
#define TI      128          // i-points per block (4 MFMA groups per A-load)
#define DEPTH   2            // prefetch depth (buffers X/Y)

__device__ __forceinline__ unsigned short f2bf(float x) {
    unsigned u = __builtin_bit_cast(unsigned, x);
    u += 0x7FFF + ((u >> 16) & 1);          // RNE
    return (unsigned short)(u >> 16);
}
__device__ __forceinline__ float bf2f(unsigned short h) {
    unsigned u = ((unsigned)h) << 16;
    return __builtin_bit_cast(float, u);
}

// ---- pack padding points into MFMA-A planes + zero the output ----
// Row j (K=16 bf16): k0-2 qh | k3-5 ql | k6-8 qh | k9-11 ql | k12-13 negc h/l |
// k14-15 = 1.0,1.0 (pair B's -ha hi/lo threshold fold).
// plane0 = k0-7 (lanes 0-31), plane1 = k8-15 (lanes 32-63).
__global__ __launch_bounds__(256) void dens_pack_kernel(
    const float* __restrict__ pad, uint4* __restrict__ ws,
    int* __restrict__ out, int M, int mtot, int N)
{
    const int j = blockIdx.x * 256 + threadIdx.x;
    if (j < N) out[j] = 0;                      // fold output zeroing here
    if (j >= mtot) return;

    float qx = 0.f, qy = 0.f, qz = 0.f;
    float negc = -1.0e6f;                       // padded rows: s<0 -> sign -1 cancels baseline
    if (j < M) {
        qx = pad[3 * j]; qy = pad[3 * j + 1]; qz = pad[3 * j + 2];
        negc = 0.125f - 0.5f * (qx * qx + qy * qy + qz * qz);   // (r^2 - |q|^2)/2
    }
    const unsigned short xh = f2bf(qx), yh = f2bf(qy), zh = f2bf(qz);
    const unsigned short xl = f2bf(qx - bf2f(xh));
    const unsigned short yl = f2bf(qy - bf2f(yh));
    const unsigned short zl = f2bf(qz - bf2f(zh));
    const unsigned short ch = f2bf(negc);
    const unsigned short cl = f2bf(negc - bf2f(ch));

    uint4 p0, p1;
    p0.x = (unsigned)xh | ((unsigned)yh << 16);   // k0,k1
    p0.y = (unsigned)zh | ((unsigned)xl << 16);   // k2,k3
    p0.z = (unsigned)yl | ((unsigned)zl << 16);   // k4,k5
    p0.w = (unsigned)xh | ((unsigned)yh << 16);   // k6,k7
    p1.x = (unsigned)zh | ((unsigned)xl << 16);   // k8,k9
    p1.y = (unsigned)yl | ((unsigned)zl << 16);   // k10,k11
    p1.z = (unsigned)ch | ((unsigned)cl << 16);   // k12,k13
    p1.w = 0x3F803F80u;                           // k14,k15 = 1.0,1.0
    ws[j]        = p0;                            // plane0
    ws[mtot + j] = p1;                            // plane1
}

// B-frag with threshold folded into k14/k15: s = p.q + negc - ha, within <=> s>=0.
__device__ __forceinline__ void make_bfrag(const float* __restrict__ pc,
                                           int i, int N, int half, bf16x8& B)
{
    float px = 0.f, py = 0.f, pz = 0.f;
    float ha = 3.0e38f;                          // i-pad: s ~ -3e38 < 0 always
    if (i < N) {
        px = pc[3 * i]; py = pc[3 * i + 1]; pz = pc[3 * i + 2];
        ha = 0.5f * (px * px + py * py + pz * pz);   // |p|^2/2, fp32
    }
    const float nha = -ha;
    const unsigned short nhh = f2bf(nha);
    const unsigned short nhl = f2bf(nha - bf2f(nhh));   // 2-term split, err ~1e-5
    const short xh = (short)f2bf(px), yh = (short)f2bf(py), zh = (short)f2bf(pz);
    const short xl = (short)f2bf(px - bf2f((unsigned short)xh));
    const short yl = (short)f2bf(py - bf2f((unsigned short)yh));
    const short zl = (short)f2bf(pz - bf2f((unsigned short)zh));
    const short ONE = (short)0x3F80;
    const bf16x8 Blo = {xh, yh, zh, xh, yh, zh, xl, yl};                    // k0-7
    const bf16x8 Bhi = {zl, xl, yl, zl, ONE, ONE, (short)nhh, (short)nhl};  // k8-15
    B = half ? Bhi : Blo;
}

// ---- packed sign-byte gather: 4 f32 D values -> 1 word of 4 bytes {0x80|0} ----
// v_perm_b32: D.byte[i] = sel.byte[i] in 0-3 -> S1.byte[sel], 4-7 -> S0.byte[sel-4],
// 0x0C -> 0x00. byte3 of an f32 = sign|exp[7:1]; AND 0x80 isolates the sign.
// Byte order within the word is irrelevant (all 32 indicators are summed).
__device__ __forceinline__ unsigned pack4(float f0, float f1, float f2, float f3) {
    const unsigned u0 = __builtin_bit_cast(unsigned, f0);
    const unsigned u1 = __builtin_bit_cast(unsigned, f1);
    const unsigned u2 = __builtin_bit_cast(unsigned, f2);
    const unsigned u3 = __builtin_bit_cast(unsigned, f3);
    const unsigned lo = __builtin_amdgcn_perm(u0, u1, 0x0C0C0703u);  // {u1.b3,u0.b3,0,0}
    const unsigned hi = __builtin_amdgcn_perm(u2, u3, 0x07030C0Cu);  // {0,0,u3.b3,u2.b3}
    return (lo | hi) & 0x80808080u;
}

// ONE i8 MFMA reduces a packed D bank: A row r = lane&31 = local i; lane-halves
// supply k=0..15 / 16..31 -> all 32 j-indicators summed per i. A bytes are
// -128 (miss) / 0 (within); B mask 0x01 only in group-g's 8 cols -> four
// i-groups share one 16-reg i32 acc. acc = -128 * miss.
__device__ __forceinline__ int32x16 red_group(const f32x16 d, int32x4 m, int32x16 acc) {
    int32x4 P;
    P[0] = (int)pack4(d[0],  d[1],  d[2],  d[3]);
    P[1] = (int)pack4(d[4],  d[5],  d[6],  d[7]);
    P[2] = (int)pack4(d[8],  d[9],  d[10], d[11]);
    P[3] = (int)pack4(d[12], d[13], d[14], d[15]);
    return __builtin_amdgcn_mfma_i32_32x32x32_i8(P, m, acc, 0, 0, 0);
}

// grid (157 x 13), 256 thr. 128-wide i-tile; 52 wave-streams stride j-tiles.
// FINAL (R9, best-measured 81.9 us total): compiler-scheduled intrinsics,
// single i8 accumulator. Series R0-R13 probed instruction mix, prefetch
// depth, L2 phasing, occupancy 2-5 waves/SIMD, load count, pipe assignment,
// and acc-chain depth — all null or regressions vs this configuration.
// 16 visits, 8 iterations of 2 visits; DEPTH=2 marching buffers X/Y.
__global__ __launch_bounds__(256, 4) void dens_mfma_kernel(
    const float* __restrict__ pc,     // [N,3] pointcloud
    const char*  __restrict__ wsA,    // packed A planes ((visits+DEPTH)*STREAMS tiles)
    int* __restrict__ out,            // [N] counts (pre-zeroed)
    int N, int iters, int p1off, int visits)
{
    const int lane = threadIdx.x & 63;
    const int w    = threadIdx.x >> 6;   // wave 0..3
    const int n    = lane & 31;          // output col within 32-tile = i
    const int half = lane >> 5;          // k-chunk 0/1

    const int ibase = blockIdx.x * TI;
    bf16x8 B0, B1, B2, B3;
    make_bfrag(pc, ibase + n,      N, half, B0);
    make_bfrag(pc, ibase + 32 + n, N, half, B1);
    make_bfrag(pc, ibase + 64 + n, N, half, B2);
    make_bfrag(pc, ibase + 96 + n, N, half, B3);

    // per-group column masks for the i8 reduction B operand: lane covers
    // output col (lane&31); group g owns cols 8g..8g+7 of the shared acc.
    const int gsel = n >> 3;
    const int m0 = (gsel == 0) ? 0x01010101 : 0;
    const int m1 = (gsel == 1) ? 0x01010101 : 0;
    const int m2 = (gsel == 2) ? 0x01010101 : 0;
    const int m3 = (gsel == 3) ? 0x01010101 : 0;
    const int32x4 R0 = {m0, m0, m0, m0};
    const int32x4 R1 = {m1, m1, m1, m1};
    const int32x4 R2 = {m2, m2, m2, m2};
    const int32x4 R3 = {m3, m3, m3, m3};

    const int stream = blockIdx.y * 4 + w;          // 0..51
    // marching A-plane pointer; tile stride 0x6800 B = 1664 uint4
    const uint4* __restrict__ ap = (const uint4*)
        (wsA + (half ? p1off : 0) + n * 16 + (size_t)stream * 512);
    const int T4 = 0x6800 / 16;

    const f32x16  z   = {0.f};      // zero C operand, held in regs
    int32x16      acc = {0};        // persistent i32 accumulator

    uint4 X = ap[0];
    uint4 Y = ap[T4];
    int nextoff = 2 * T4;

#define GROUPV(AV, BV, RV) { \
        f32x16 d = __builtin_amdgcn_mfma_f32_32x32x16_bf16(AV, BV, z, 0, 0, 0); \
        acc = red_group(d, RV, acc); }

    for (int t = 0; t < iters; ++t) {
        {   // visit A: consume X, refill X two tiles ahead
            const bf16x8 a = __builtin_bit_cast(bf16x8, X);
            GROUPV(a, B0, R0)
            GROUPV(a, B1, R1)
            GROUPV(a, B2, R2)
            GROUPV(a, B3, R3)
            X = ap[nextoff]; nextoff += T4;
        }
        {   // visit B: consume Y, refill Y
            const bf16x8 a = __builtin_bit_cast(bf16x8, Y);
            GROUPV(a, B0, R0)
            GROUPV(a, B1, R1)
            GROUPV(a, B2, R2)
            GROUPV(a, B3, R3)
            Y = ap[nextoff]; nextoff += T4;
        }
    }
#undef GROUPV

    // acc D-layout (32x32 i32): col = lane&31 (group g = col>>3, value
    // replicated across the 8 cols of its range), row = (q&3)+8*(q>>2)+4*half
    // = local i. acc = -128 * (#not-within) over this wave's 32*visits j's
    // -> per-i count for this wave = 32*visits + (acc >> 7).
    const int base = 32 * visits;
    __shared__ int red[4][TI];
    if ((lane & 7) == 0) {                       // one writer per (group,half)
        const int g   = n >> 3;
        const int hi4 = half << 2;               // +4 rows for upper lane-half
        int* rw = &red[w][32 * g];
        rw[ 0 + hi4] = base + (acc[0]  >> 7);
        rw[ 1 + hi4] = base + (acc[1]  >> 7);
        rw[ 2 + hi4] = base + (acc[2]  >> 7);
        rw[ 3 + hi4] = base + (acc[3]  >> 7);
        rw[ 8 + hi4] = base + (acc[4]  >> 7);
        rw[ 9 + hi4] = base + (acc[5]  >> 7);
        rw[10 + hi4] = base + (acc[6]  >> 7);
        rw[11 + hi4] = base + (acc[7]  >> 7);
        rw[16 + hi4] = base + (acc[8]  >> 7);
        rw[17 + hi4] = base + (acc[9]  >> 7);
        rw[18 + hi4] = base + (acc[10] >> 7);
        rw[19 + hi4] = base + (acc[11] >> 7);
        rw[24 + hi4] = base + (acc[12] >> 7);
        rw[25 + hi4] = base + (acc[13] >> 7);
        rw[26 + hi4] = base + (acc[14] >> 7);
        rw[27 + hi4] = base + (acc[15] >> 7);
    }
    __syncthreads();
    if (threadIdx.x < TI) {
        const int ii = ibase + threadIdx.x;
        if (ii < N) {
            const int s = red[0][threadIdx.x] + red[1][threadIdx.x] +
                          red[2][threadIdx.x] + red[3][threadIdx.x];
            atomicAdd(&out[ii], s);
        }
    }
}

extern "C" void kernel_launch(void* const* d_in, const int* in_sizes, int n_in,
                              void* d_out, int out_size, void* d_ws, size_t ws_size,
                              hipStream_t stream) {
    const float* pc  = (const float*)d_in[0];   // [N,3] pointcloud
    const float* pad = (const float*)d_in[1];   // [M,3] pointcloud_padding
    int* out = (int*)d_out;

    const int N = in_sizes[0] / 3;              // 20000
    const int M = in_sizes[1] / 3;              // 25000
    const int jt = (M + 31) / 32;               // 782 j-tiles
    int visits = (jt + STREAMS - 1) / STREAMS;  // 16
    if (visits & 1) visits++;                   // 2-visit unrolled body
    const int jtp  = (visits + DEPTH) * STREAMS;    // 936 tiles incl. prefetch overrun
    const int mtot = jtp * 32;                  // 29952 rows (~958 KB in ws)

    dens_pack_kernel<<<(mtot + 255) / 256, 256, 0, stream>>>(
        pad, (uint4*)d_ws, out, M, mtot, N);

    dim3 grid((N + TI - 1) / TI, JS);           // 157 x 13
    dens_mfma_kernel<<<grid, 256, 0, stream>>>(
        pc, (const char*)d_ws, out, N, visits / 2, mtot * 16, visits);
}